// Round 7
// baseline (208.760 us; speedup 1.0000x reference)
//
#include <hip/hip_runtime.h>
#include <math.h>

#define BB 16
#define NN 2048
#define MM 16
#define SS 128

__constant__ const float kFourPi = 12.566370614359172f;

// ---------------------------------------------------------------------------
// Kernel 1 (prep): pack pcl -> PclP[bm][n] = float4(x,y,z, 0.5*|q|^2)
//                  pack prim -> PrimP[bm][s] = float4(x,y,z, 0.5*|p|^2)
// grid (16, 17): y<16 = pcl tile (b, n0=y*128); y==16 = prim for b.
// Block (0,0) zeroes flags[0..15] (per-b producer counters) and flags[16]
// (p2p completion counter).
// ---------------------------------------------------------------------------
__global__ __launch_bounds__(256) void prep_kernel(
    const float* __restrict__ pcl,    // (B,N,M,3)
    const float* __restrict__ prim,   // (B,M,S,3)
    float4* __restrict__ PclP,        // [256][2048]
    float4* __restrict__ PrimP,       // [256][128]
    unsigned int* __restrict__ flags) // [17]
{
    const int b   = blockIdx.x;
    const int tid = threadIdx.x;

    if (blockIdx.x == 0 && blockIdx.y == 0 && tid < 17)
        __hip_atomic_store(&flags[tid], 0u, __ATOMIC_RELAXED, __HIP_MEMORY_SCOPE_AGENT);

    if (blockIdx.y < 16) {
        // pcl tile: 128 n x 16 m x 3
        const int n0 = blockIdx.y * 128;
        __shared__ float q[6144];
        const float4* src = (const float4*)(pcl + ((size_t)b * NN + n0) * (MM * 3));
        float4* qv = (float4*)q;
#pragma unroll
        for (int k = 0; k < 6; ++k)
            qv[tid + k * 256] = src[tid + k * 256];
        __syncthreads();

        const int n  = tid & 127;
        const int mh = tid >> 7;           // 0 or 1
#pragma unroll
        for (int k = 0; k < 8; ++k) {
            const int m = k * 2 + mh;
            const float x = q[(n * 16 + m) * 3 + 0];
            const float y = q[(n * 16 + m) * 3 + 1];
            const float z = q[(n * 16 + m) * 3 + 2];
            const float h = 0.5f * (x * x + y * y + z * z);
            PclP[((size_t)(b * MM + m)) * NN + n0 + n] = make_float4(x, y, z, h);
        }
    } else {
        // prim for this b: 2048 points (m*128+s), contiguous
        const float* pp = prim + (size_t)b * (MM * SS * 3);
#pragma unroll
        for (int k = 0; k < 8; ++k) {
            const int p = tid + k * 256;
            const float x = pp[p * 3 + 0];
            const float y = pp[p * 3 + 1];
            const float z = pp[p * 3 + 2];
            const float h = 0.5f * (x * x + y * y + z * z);
            PrimP[(size_t)b * (MM * SS) + p] = make_float4(x, y, z, h);
        }
    }
}

// ---------------------------------------------------------------------------
// Mega kernel: grid 1024 x 256 threads.
// Phase A (all blocks): dist tile (bm = id>>2, cs = id&3); e = d/2 via dot
// expansion; d1part[cs][bm][n] + d2part[cs*256+bm]; release flags[b].
// Phase B (blocks 0..127): spin-acquire flags[b]==64, then p2p sort +
// stick-breaking for 256 (b,n) rows; last block finalizes outputs.
// Deadlock-safe: only 128 blocks spin, each after finishing its producer
// tile; >=3 blocks/CU resident capacity (768) >> 128 spinners.
// ---------------------------------------------------------------------------
__global__ __launch_bounds__(256, 4) void mega_kernel(
    const float4* __restrict__ PclP,   // [256][2048]
    const float4* __restrict__ PrimP,  // [256][128]
    float* __restrict__ d1part,        // [4][256][2048]  (e-scale)
    float* __restrict__ d2part,        // [4][256]        (d-scale)
    const float* __restrict__ probs,   // (B,M)
    const float* __restrict__ size_,   // (B,M,3)
    float* __restrict__ partial,       // [128]
    unsigned int* __restrict__ flags,  // [17]
    float* __restrict__ out)           // (4)
{
    const int id  = blockIdx.x;
    const int bm  = id >> 2;
    const int cs  = id & 3;
    const int b   = bm >> 4;
    const int tid = threadIdx.x;
    const int wid  = tid >> 6;
    const int lane = tid & 63;

    __shared__ float4 Plds[32];
    __shared__ float  wred[4][64];

    // ---------------- Phase A: dist ----------------
    if (tid < 32)
        Plds[tid] = PrimP[(size_t)bm * SS + cs * 32 + tid];

    float qx[8], qy[8], qz[8], hq[8], d1m[8];
    const float4* qp = PclP + (size_t)bm * NN + tid;
#pragma unroll
    for (int j = 0; j < 8; ++j) {
        const float4 q = qp[j * 256];
        qx[j] = q.x; qy[j] = q.y; qz[j] = q.z; hq[j] = q.w;
        d1m[j] = 3.0e38f;
    }
    __syncthreads();

    float d2r[32];
#pragma unroll
    for (int s = 0; s < 32; ++s) {
        const float4 f = Plds[s];              // lane-uniform ds_read_b128
        float e[8];
#pragma unroll
        for (int j = 0; j < 8; ++j) {
            float t = hq[j] + f.w;             // 0.5|q|^2 + 0.5|p|^2
            t = fmaf(f.x, -qx[j], t);
            t = fmaf(f.y, -qy[j], t);
            t = fmaf(f.z, -qz[j], t);
            e[j] = t;
            d1m[j] = fminf(d1m[j], t);
        }
        const float m01 = fminf(e[0], e[1]);
        const float m23 = fminf(e[2], e[3]);
        const float m45 = fminf(e[4], e[5]);
        const float m67 = fminf(e[6], e[7]);
        d2r[s] = fminf(fminf(m01, m23), fminf(m45, m67));
    }

    // d1 write (e-scale), coalesced; kills d1m early
    {
        float* dd = d1part + ((size_t)(cs * 256 + bm)) * NN + tid;
#pragma unroll
        for (int j = 0; j < 8; ++j) dd[j * 256] = d1m[j];
    }

    // d2: dimension-folding wave reduction (32 vals -> 1 per lane)
    float v16[16];
    {
        const bool hi = (lane & 32) != 0;
#pragma unroll
        for (int k = 0; k < 16; ++k) {
            const float xk = hi ? d2r[k + 16] : d2r[k];
            const float xs = hi ? d2r[k] : d2r[k + 16];
            v16[k] = fminf(xk, __shfl_xor(xs, 32, 64));
        }
    }
    float v8[8];
    {
        const bool hi = (lane & 16) != 0;
#pragma unroll
        for (int k = 0; k < 8; ++k) {
            const float xk = hi ? v16[k + 8] : v16[k];
            const float xs = hi ? v16[k] : v16[k + 8];
            v8[k] = fminf(xk, __shfl_xor(xs, 16, 64));
        }
    }
    float v4[4];
    {
        const bool hi = (lane & 8) != 0;
#pragma unroll
        for (int k = 0; k < 4; ++k) {
            const float xk = hi ? v8[k + 4] : v8[k];
            const float xs = hi ? v8[k] : v8[k + 4];
            v4[k] = fminf(xk, __shfl_xor(xs, 8, 64));
        }
    }
    float v2a, v2b;
    {
        const bool hi = (lane & 4) != 0;
        const float xk0 = hi ? v4[2] : v4[0];
        const float xs0 = hi ? v4[0] : v4[2];
        v2a = fminf(xk0, __shfl_xor(xs0, 4, 64));
        const float xk1 = hi ? v4[3] : v4[1];
        const float xs1 = hi ? v4[1] : v4[3];
        v2b = fminf(xk1, __shfl_xor(xs1, 4, 64));
    }
    float v1;
    {
        const bool hi = (lane & 2) != 0;
        const float xk = hi ? v2b : v2a;
        const float xs = hi ? v2a : v2b;
        v1 = fminf(xk, __shfl_xor(xs, 2, 64));
    }
    const float r = fminf(v1, __shfl_xor(v1, 1, 64));  // 64-lane min, s = lane bits[5:1]
    wred[wid][lane] = r;
    __syncthreads();

    if (tid < 64) {
        float mv = fminf(fminf(wred[0][tid], wred[1][tid]),
                         fminf(wred[2][tid], wred[3][tid]));
        if (mv >= 5.0e29f) mv = 0.0f;          // clamp at e-scale (d >= 1e30)
        // sum over 64 lanes = 2 * sum_s e_min = sum_s d_min (x2 dup cancels)
#pragma unroll
        for (int off = 32; off > 0; off >>= 1)
            mv += __shfl_down(mv, off, 64);
        if (tid == 0) d2part[cs * 256 + bm] = mv;
    }

    // release this tile: all threads fence, then one add per block
    __threadfence();
    __syncthreads();
    if (tid == 0)
        __hip_atomic_fetch_add(&flags[b], 1u, __ATOMIC_RELEASE, __HIP_MEMORY_SCOPE_AGENT);

    if (id >= 128) return;

    // ---------------- Phase B: p2p (blocks 0..127) ----------------
    const int wb = id >> 3;                    // batch this block consumes
    while (__hip_atomic_load(&flags[wb], __ATOMIC_ACQUIRE, __HIP_MEMORY_SCOPE_AGENT) < 64u)
        __builtin_amdgcn_s_sleep(2);

    const int gid = id * 256 + tid;            // b*N + n  (b == wb)
    const int n   = gid & (NN - 1);

    float d[16], p[16];
#pragma unroll
    for (int m = 0; m < 16; ++m) {
        const size_t base = ((size_t)(wb * MM + m)) * NN + n;
        const float u0 = d1part[base];
        const float u1 = d1part[base + (size_t)256 * NN];
        const float u2 = d1part[base + (size_t)512 * NN];
        const float u3 = d1part[base + (size_t)768 * NN];
        const float mn = fminf(fminf(u0, u1), fminf(u2, u3));
        d[m] = mn + mn;                        // e -> d
    }

    const float* pb = probs + wb * MM;
#pragma unroll
    for (int k = 0; k < 16; ++k) p[k] = pb[k];

#define CE(i, j)                                              \
    {                                                         \
        const bool c = d[i] > d[j];                           \
        const float td = c ? d[j] : d[i];                     \
        d[j] = c ? d[i] : d[j];  d[i] = td;                   \
        const float tp = c ? p[j] : p[i];                     \
        p[j] = c ? p[i] : p[j];  p[i] = tp;                   \
    }
#pragma unroll
    for (int rr = 0; rr < 16; ++rr) {
        if ((rr & 1) == 0) {
            CE(0, 1) CE(2, 3) CE(4, 5) CE(6, 7)
            CE(8, 9) CE(10, 11) CE(12, 13) CE(14, 15)
        } else {
            CE(1, 2) CE(3, 4) CE(5, 6) CE(7, 8)
            CE(9, 10) CE(11, 12) CE(13, 14)
        }
    }
#undef CE

    float acc = 1.0f, sum = 0.0f;
#pragma unroll
    for (int k = 0; k < 16; ++k) {
        sum += d[k] * p[k] * acc;
        acc *= (1.0f - p[k]);
    }

    __shared__ float red4[4];
#pragma unroll
    for (int off = 32; off > 0; off >>= 1)
        sum += __shfl_down(sum, off, 64);
    if (lane == 0) red4[wid] = sum;
    __syncthreads();

    __shared__ bool amLast;
    if (tid == 0) {
        const float bsum = red4[0] + red4[1] + red4[2] + red4[3];
        __hip_atomic_store(&partial[id], bsum,
                           __ATOMIC_RELEASE, __HIP_MEMORY_SCOPE_AGENT);
        const unsigned int prev = __hip_atomic_fetch_add(
            &flags[16], 1u, __ATOMIC_ACQ_REL, __HIP_MEMORY_SCOPE_AGENT);
        amLast = (prev == 127u);
    }
    __syncthreads();
    if (!amLast) return;

    // ---------------- finalize (one block; tid == b*16 + m) ----------------
    const int fb = tid >> 4;

    __shared__ float  areaSh[256];
    __shared__ double redA[4];
    __shared__ double redB[4];

    const float s0 = size_[tid * 3 + 0];
    const float s1 = size_[tid * 3 + 1];
    const float s2 = size_[tid * 3 + 2];
    const float inner = powf(s0 * s1, 1.6f) * (1.0f / 3.0f)
                      + powf(s0 * s2, 1.6f) * (1.0f / 3.0f)
                      + powf(s1 * s2, 1.6f) * (1.0f / 3.0f);
    const float a = kFourPi * powf(inner, 0.625f);
    areaSh[tid] = a;
    __syncthreads();

    float asum = 0.0f;
#pragma unroll
    for (int mm = 0; mm < 16; ++mm) asum += areaSh[fb * 16 + mm];
    const float anorm = 16.0f * a / asum;      // M * area / sum_m area

    const float d2s = d2part[tid] + d2part[256 + tid] + d2part[512 + tid] + d2part[768 + tid];
    double t = (double)(d2s * (1.0f / 128.0f)) * (double)probs[tid] * (double)anorm;
#pragma unroll
    for (int off = 32; off > 0; off >>= 1)
        t += __shfl_down(t, off, 64);
    if (lane == 0) redA[wid] = t;

    double u = 0.0;
    if (tid < 128) {
        const float pv = __hip_atomic_load(&partial[tid],
                                           __ATOMIC_ACQUIRE, __HIP_MEMORY_SCOPE_AGENT);
        u = (double)pv;
    }
#pragma unroll
    for (int off = 32; off > 0; off >>= 1)
        u += __shfl_down(u, off, 64);
    if (lane == 0) redB[wid] = u;

    __syncthreads();
    if (tid == 0) {
        const double prim_to_pcl = (redA[0] + redA[1] + redA[2] + redA[3]) / 256.0;    // /(B*M)
        const double pcl_to_prim = (redB[0] + redB[1] + redB[2] + redB[3]) / 32768.0;  // /(B*N)
        out[0] = (float)(pcl_to_prim + prim_to_pcl);
        out[1] = (float)pcl_to_prim;
        out[2] = (float)prim_to_pcl;
        out[3] = 0.0f;
    }
}

// ---------------------------------------------------------------------------

extern "C" void kernel_launch(void* const* d_in, const int* in_sizes, int n_in,
                              void* d_out, int out_size, void* d_ws, size_t ws_size,
                              hipStream_t stream) {
    const float* pcl   = (const float*)d_in[0];  // (B,N,M,3)
    const float* prim  = (const float*)d_in[1];  // (B,M,S,3)
    const float* size_ = (const float*)d_in[2];  // (B,M,3)
    const float* probs = (const float*)d_in[3];  // (B,M)
    float* out = (float*)d_out;

    const size_t nBMN = (size_t)BB * MM * NN;                 // 524288
    float4* PclP   = (float4*)d_ws;                           // 8 MiB
    float4* PrimP  = PclP + nBMN;                             // 512 KiB
    float*  d1part = (float*)(PrimP + (size_t)BB * MM * SS);  // 8 MiB
    float*  d2part = d1part + 4 * nBMN;                       // 1024
    float*  partial = d2part + 1024;                          // 128
    unsigned int* flags = (unsigned int*)(partial + 128);     // 17

    prep_kernel<<<dim3(BB, 17), 256, 0, stream>>>(pcl, prim, PclP, PrimP, flags);
    mega_kernel<<<1024, 256, 0, stream>>>(PclP, PrimP, d1part, d2part,
                                          probs, size_, partial, flags, out);
}

// Round 8
// 89.422 us; speedup vs baseline: 2.3345x; 2.3345x over previous
//
#include <hip/hip_runtime.h>
#include <math.h>

#define BB 16
#define NN 2048
#define MM 16
#define SS 128

__constant__ const float kFourPi = 12.566370614359172f;

// ---------------------------------------------------------------------------
// Kernel A: one block per (b,m), 1024 threads (16 waves), 1 block/CU.
// __launch_bounds__(1024, 4): 4 waves/EU min -> 128-VGPR cap (round-4's
// spill came from the default 64-VGPR cap at this block size).
// Stages pcl[b,:,m,:] (+0.5|q|^2) and prim[b,m] (+0.5|p|^2) in LDS once.
// 4 s-subgroups x 256 threads; thread: 8 n in regs, 32 s loop, e = d/2 via
// dot expansion (4 VALU/pair). d2 via register d2r[32] + dimension-fold
// (zero cross-lane ops in hot loop). Writes d1[bm][n] (e-scale, 2 MB) and
// d2sum[bm] (d-scale) directly. Block 0 zeroes kernel B's counter.
// ---------------------------------------------------------------------------
__global__ __launch_bounds__(1024, 4) void fused_dist_kernel(
    const float* __restrict__ pcl,    // (B,N,M,3)
    const float* __restrict__ prim,   // (B,M,S,3)
    float* __restrict__ d1,           // [256][2048]  (e-scale)
    float* __restrict__ d2sum,        // [256]        (d-scale)
    unsigned int* __restrict__ counter)
{
    const int bm  = blockIdx.x;
    const int b   = bm >> 4;
    const int m   = bm & 15;
    const int tid = threadIdx.x;

    __shared__ float  Qx[NN], Qy[NN], Qz[NN], Qh[NN];  // 32 KB
    __shared__ float4 Plds[SS];                        // 2 KB (x,y,z,hp)
    __shared__ float  d1s[4][NN];                      // 32 KB
    __shared__ float  wred[16][64];                    // 4 KB
    __shared__ float  rsum[4];

    if (bm == 0 && tid == 0)
        __hip_atomic_store(counter, 0u, __ATOMIC_RELAXED, __HIP_MEMORY_SCOPE_AGENT);

    // stage pcl[b,:,m,:] (12B-of-192B scatter, read exactly once) + hq
    {
        const size_t base = ((size_t)(b * NN) * MM + m) * 3;
#pragma unroll
        for (int j = 0; j < 2; ++j) {
            const int n = tid + j * 1024;
            const float* q = pcl + base + (size_t)n * (MM * 3);
            const float x = q[0], y = q[1], z = q[2];
            Qx[n] = x; Qy[n] = y; Qz[n] = z;
            Qh[n] = 0.5f * (x * x + y * y + z * z);
        }
    }
    if (tid < SS) {
        const float* pp = prim + ((size_t)bm * SS + tid) * 3;
        const float x = pp[0], y = pp[1], z = pp[2];
        Plds[tid] = make_float4(x, y, z, 0.5f * (x * x + y * y + z * z));
    }
    __syncthreads();

    const int sub  = tid >> 8;    // s-chunk 0..3
    const int stid = tid & 255;
    const int s0   = sub * 32;
    const int wid  = tid >> 6;    // 0..15
    const int lane = tid & 63;

    float qx[8], qy[8], qz[8], hq[8], d1m[8];
#pragma unroll
    for (int j = 0; j < 8; ++j) {
        const int n = stid + j * 256;
        qx[j] = Qx[n]; qy[j] = Qy[n]; qz[j] = Qz[n]; hq[j] = Qh[n];
        d1m[j] = 3.0e38f;
    }

    float d2r[32];
#pragma unroll
    for (int s = 0; s < 32; ++s) {
        const float4 f = Plds[s0 + s];         // wave-uniform ds_read_b128
        float e[8];
#pragma unroll
        for (int j = 0; j < 8; ++j) {
            float t = hq[j] + f.w;             // 0.5|q|^2 + 0.5|p|^2
            t = fmaf(f.x, -qx[j], t);
            t = fmaf(f.y, -qy[j], t);
            t = fmaf(f.z, -qz[j], t);
            e[j] = t;
            d1m[j] = fminf(d1m[j], t);
        }
        const float m01 = fminf(e[0], e[1]);
        const float m23 = fminf(e[2], e[3]);
        const float m45 = fminf(e[4], e[5]);
        const float m67 = fminf(e[6], e[7]);
        d2r[s] = fminf(fminf(m01, m23), fminf(m45, m67));
    }

    // d1: combine 4 s-chunks in LDS, coalesced e-scale global write
#pragma unroll
    for (int j = 0; j < 8; ++j)
        d1s[sub][stid + j * 256] = d1m[j];
    __syncthreads();
#pragma unroll
    for (int j = 0; j < 2; ++j) {
        const int n = tid + j * 1024;
        d1[(size_t)bm * NN + n] = fminf(fminf(d1s[0][n], d1s[1][n]),
                                        fminf(d1s[2][n], d1s[3][n]));
    }

    // --- d2: dimension-folding wave reduction (32 vals -> 1 per lane) ---
    float v16[16];
    {
        const bool hi = (lane & 32) != 0;
#pragma unroll
        for (int k = 0; k < 16; ++k) {
            const float xk = hi ? d2r[k + 16] : d2r[k];
            const float xs = hi ? d2r[k] : d2r[k + 16];
            v16[k] = fminf(xk, __shfl_xor(xs, 32, 64));
        }
    }
    float v8[8];
    {
        const bool hi = (lane & 16) != 0;
#pragma unroll
        for (int k = 0; k < 8; ++k) {
            const float xk = hi ? v16[k + 8] : v16[k];
            const float xs = hi ? v16[k] : v16[k + 8];
            v8[k] = fminf(xk, __shfl_xor(xs, 16, 64));
        }
    }
    float v4[4];
    {
        const bool hi = (lane & 8) != 0;
#pragma unroll
        for (int k = 0; k < 4; ++k) {
            const float xk = hi ? v8[k + 4] : v8[k];
            const float xs = hi ? v8[k] : v8[k + 4];
            v4[k] = fminf(xk, __shfl_xor(xs, 8, 64));
        }
    }
    float v2a, v2b;
    {
        const bool hi = (lane & 4) != 0;
        const float xk0 = hi ? v4[2] : v4[0];
        const float xs0 = hi ? v4[0] : v4[2];
        v2a = fminf(xk0, __shfl_xor(xs0, 4, 64));
        const float xk1 = hi ? v4[3] : v4[1];
        const float xs1 = hi ? v4[1] : v4[3];
        v2b = fminf(xk1, __shfl_xor(xs1, 4, 64));
    }
    float v1;
    {
        const bool hi = (lane & 2) != 0;
        const float xk = hi ? v2b : v2a;
        const float xs = hi ? v2a : v2b;
        v1 = fminf(xk, __shfl_xor(xs, 2, 64));
    }
    // lane holds min over its wave's 512 n for s = s0 + bits[5:1], dup x2
    const float r = fminf(v1, __shfl_xor(v1, 1, 64));
    wred[wid][lane] = r;
    __syncthreads();

    // combine the 4 waves of each sub-group (-> min over all 2048 n), clamp,
    // sum: 64-lane sum = 2 * sum_s e_min = sum_s d_min  (x2 dup cancels)
    if (tid < 256) {                 // waves 0..3, fully active
        const int sc = tid >> 6;     // s-chunk this wave combines
        const int l  = tid & 63;
        float mv = fminf(fminf(wred[sc * 4 + 0][l], wred[sc * 4 + 1][l]),
                         fminf(wred[sc * 4 + 2][l], wred[sc * 4 + 3][l]));
        if (mv >= 5.0e29f) mv = 0.0f;          // clamp at e-scale (d >= 1e30)
#pragma unroll
        for (int off = 32; off > 0; off >>= 1)
            mv += __shfl_down(mv, off, 64);
        if (l == 0) rsum[sc] = mv;
    }
    __syncthreads();
    if (tid == 0) d2sum[bm] = rsum[0] + rsum[1] + rsum[2] + rsum[3];
}

// ---------------------------------------------------------------------------
// Kernel B: p2p sort + stick-breaking; last block finalizes.
// grid 128 x 256; one thread per (b,n).
// ---------------------------------------------------------------------------
__global__ __launch_bounds__(256) void p2p_final_kernel(
    const float* __restrict__ d1,      // [256][2048] (e-scale)
    const float* __restrict__ probs,   // (B,M)
    const float* __restrict__ size_,   // (B,M,3)
    const float* __restrict__ d2sum,   // [256]
    float* __restrict__ partial,       // [128]
    unsigned int* __restrict__ counter,
    float* __restrict__ out)           // (4)
{
    const int tid = threadIdx.x;
    const int gid = blockIdx.x * 256 + tid;   // b*N + n
    const int b   = gid >> 11;
    const int n   = gid & (NN - 1);

    float d[16], p[16];
#pragma unroll
    for (int m = 0; m < 16; ++m) {
        const float mn = d1[((size_t)(b * MM + m)) * NN + n];
        d[m] = mn + mn;                       // e -> d
    }

    const float* pb = probs + b * MM;
#pragma unroll
    for (int k = 0; k < 16; ++k) p[k] = pb[k];

#define CE(i, j)                                              \
    {                                                         \
        const bool c = d[i] > d[j];                           \
        const float td = c ? d[j] : d[i];                     \
        d[j] = c ? d[i] : d[j];  d[i] = td;                   \
        const float tp = c ? p[j] : p[i];                     \
        p[j] = c ? p[i] : p[j];  p[i] = tp;                   \
    }
#pragma unroll
    for (int r = 0; r < 16; ++r) {
        if ((r & 1) == 0) {
            CE(0, 1) CE(2, 3) CE(4, 5) CE(6, 7)
            CE(8, 9) CE(10, 11) CE(12, 13) CE(14, 15)
        } else {
            CE(1, 2) CE(3, 4) CE(5, 6) CE(7, 8)
            CE(9, 10) CE(11, 12) CE(13, 14)
        }
    }
#undef CE

    float acc = 1.0f, sum = 0.0f;
#pragma unroll
    for (int k = 0; k < 16; ++k) {
        sum += d[k] * p[k] * acc;
        acc *= (1.0f - p[k]);
    }

    const int wid  = tid >> 6;
    const int lane = tid & 63;
    __shared__ float red4[4];
#pragma unroll
    for (int off = 32; off > 0; off >>= 1)
        sum += __shfl_down(sum, off, 64);
    if (lane == 0) red4[wid] = sum;
    __syncthreads();

    __shared__ bool amLast;
    if (tid == 0) {
        const float bsum = red4[0] + red4[1] + red4[2] + red4[3];
        __hip_atomic_store(&partial[blockIdx.x], bsum,
                           __ATOMIC_RELEASE, __HIP_MEMORY_SCOPE_AGENT);
        const unsigned int prev = __hip_atomic_fetch_add(
            counter, 1u, __ATOMIC_ACQ_REL, __HIP_MEMORY_SCOPE_AGENT);
        amLast = (prev == 127u);
    }
    __syncthreads();
    if (!amLast) return;

    // ---- finalize (one block; tid == b*16 + m) ----
    const int fb = tid >> 4;

    __shared__ float  areaSh[256];
    __shared__ double redA[4];
    __shared__ double redB[4];

    const float s0 = size_[tid * 3 + 0];
    const float s1 = size_[tid * 3 + 1];
    const float s2 = size_[tid * 3 + 2];
    const float inner = powf(s0 * s1, 1.6f) * (1.0f / 3.0f)
                      + powf(s0 * s2, 1.6f) * (1.0f / 3.0f)
                      + powf(s1 * s2, 1.6f) * (1.0f / 3.0f);
    const float a = kFourPi * powf(inner, 0.625f);
    areaSh[tid] = a;
    __syncthreads();

    float asum = 0.0f;
#pragma unroll
    for (int mm = 0; mm < 16; ++mm) asum += areaSh[fb * 16 + mm];
    const float anorm = 16.0f * a / asum;   // M * area / sum_m area

    double t = (double)(d2sum[tid] * (1.0f / 128.0f)) * (double)probs[tid] * (double)anorm;
#pragma unroll
    for (int off = 32; off > 0; off >>= 1)
        t += __shfl_down(t, off, 64);
    if (lane == 0) redA[wid] = t;

    double u = 0.0;
    if (tid < 128) {
        const float pv = __hip_atomic_load(&partial[tid],
                                           __ATOMIC_ACQUIRE, __HIP_MEMORY_SCOPE_AGENT);
        u = (double)pv;
    }
#pragma unroll
    for (int off = 32; off > 0; off >>= 1)
        u += __shfl_down(u, off, 64);
    if (lane == 0) redB[wid] = u;

    __syncthreads();
    if (tid == 0) {
        const double prim_to_pcl = (redA[0] + redA[1] + redA[2] + redA[3]) / 256.0;    // /(B*M)
        const double pcl_to_prim = (redB[0] + redB[1] + redB[2] + redB[3]) / 32768.0;  // /(B*N)
        out[0] = (float)(pcl_to_prim + prim_to_pcl);
        out[1] = (float)pcl_to_prim;
        out[2] = (float)prim_to_pcl;
        out[3] = 0.0f;
    }
}

// ---------------------------------------------------------------------------

extern "C" void kernel_launch(void* const* d_in, const int* in_sizes, int n_in,
                              void* d_out, int out_size, void* d_ws, size_t ws_size,
                              hipStream_t stream) {
    const float* pcl   = (const float*)d_in[0];  // (B,N,M,3)
    const float* prim  = (const float*)d_in[1];  // (B,M,S,3)
    const float* size_ = (const float*)d_in[2];  // (B,M,3)
    const float* probs = (const float*)d_in[3];  // (B,M)
    float* out = (float*)d_out;

    float* d1             = (float*)d_ws;             // 256*2048 floats (2 MiB)
    float* d2sum          = d1 + (size_t)256 * NN;    // 256
    float* partial        = d2sum + 256;              // 128
    unsigned int* counter = (unsigned int*)(partial + 128);

    fused_dist_kernel<<<BB * MM, 1024, 0, stream>>>(pcl, prim, d1, d2sum, counter);
    p2p_final_kernel<<<128, 256, 0, stream>>>(d1, probs, size_, d2sum, partial, counter, out);
}